// Round 13
// baseline (141.396 us; speedup 1.0000x reference)
//
#include <hip/hip_runtime.h>
#include <hip/hip_bf16.h>

#define LSEQ 2048
#define DM   1024
#define NH   16

typedef __attribute__((ext_vector_type(8)))  short bf16x8;
typedef __attribute__((ext_vector_type(8)))  unsigned short u16x8;
typedef __attribute__((ext_vector_type(4)))  float f32x4;
typedef __attribute__((ext_vector_type(16))) float f32x16;
typedef __attribute__((ext_vector_type(4)))  unsigned int u32x4;

#define LOG2E 1.4426950408889634f
#define C1SC  0.18033688011112042f   /* 0.125 * log2(e) */

static __device__ __forceinline__ float exp2fast(float x) {
  return __builtin_amdgcn_exp2f(x);
}

static __device__ __forceinline__ unsigned short f2bf(float f) {
  unsigned int u = __float_as_uint(f);
  u += 0x7FFFu + ((u >> 16) & 1u);
  return (unsigned short)(u >> 16);
}

static __device__ __forceinline__ unsigned pk2(float a, float b) {
  __hip_bfloat162 t = __float22bfloat162_rn(make_float2(a, b));
  return *reinterpret_cast<unsigned*>(&t);
}

// unpack 16 packed bf16 (two 16B vectors) -> f32x16
static __device__ __forceinline__ f32x16 unpack16(u16x8 a, u16x8 b) {
  const u32x4 ua = __builtin_bit_cast(u32x4, a);
  const u32x4 ub = __builtin_bit_cast(u32x4, b);
  f32x16 r;
#pragma unroll
  for (int i = 0; i < 4; ++i) {
    r[2 * i]     = __uint_as_float(ua[i] << 16);
    r[2 * i + 1] = __uint_as_float(ua[i] & 0xFFFF0000u);
    r[8 + 2 * i]     = __uint_as_float(ub[i] << 16);
    r[8 + 2 * i + 1] = __uint_as_float(ub[i] & 0xFFFF0000u);
  }
  return r;
}

// pack 8 floats (natural order) -> PV B-fragment (V is k-permuted to match)
static __device__ __forceinline__ bf16x8 pack8(const f32x16& s, int base) {
  u32x4 w;
  w[0] = pk2(s[base + 0], s[base + 1]); w[1] = pk2(s[base + 2], s[base + 3]);
  w[2] = pk2(s[base + 4], s[base + 5]); w[3] = pk2(s[base + 6], s[base + 7]);
  return __builtin_bit_cast(bf16x8, w);
}

static __device__ __forceinline__ void gld_lds16(const unsigned short* g, unsigned short* l) {
  __builtin_amdgcn_global_load_lds(
      (const __attribute__((address_space(1))) unsigned int*)g,
      (__attribute__((address_space(3))) unsigned int*)l, 16, 0, 0);
}

// ---------------- rotary table: rot[(b*LSEQ+l)*64+d] = (cos, sign*sin) ----------------
// Stored in d_out (dead until k_attn fully overwrites it). 2 MB.
__global__ void k_rotary(const float* __restrict__ temporal, float2* __restrict__ rot) {
  int i = blockIdx.x * 256 + threadIdx.x;            // over 2*LSEQ*64 = 262144
  if (i >= 2 * LSEQ * 64) return;
  const int d = i & 63, l = i >> 6;                  // l = b*LSEQ + lseq
  const float t = temporal[l * 4 + (d >> 4)];
  const float fr = __expf(-(float)(d & 14) * 0.5756462732485115f);
  float sn, cs;
  __sincosf(t * fr, &sn, &cs);
  rot[i] = make_float2(cs, (d & 1) ? sn : -sn);
}

// ---------------- data fp32 -> bf16 ----------------
__global__ void k_convert_data(const float* __restrict__ src,
                               unsigned short* __restrict__ dst, int n4) {
  int i = blockIdx.x * 256 + threadIdx.x;
  if (i >= n4) return;
  float4 v = reinterpret_cast<const float4*>(src)[i];
  ushort4 o;
  o.x = f2bf(v.x); o.y = f2bf(v.y); o.z = f2bf(v.z); o.w = f2bf(v.w);
  reinterpret_cast<ushort4*>(dst)[i] = o;
}

// ---------------- W -> Wt bf16 (transpose to [n][k]) ----------------
__global__ void k_transpose_w(const float* __restrict__ Wq,
                              const float* __restrict__ Wk,
                              const float* __restrict__ Wv,
                              unsigned short* __restrict__ Wt) {
  __shared__ unsigned short tile[64][65];
  const float* W = (blockIdx.z == 0) ? Wq : (blockIdx.z == 1) ? Wk : Wv;
  int n0 = blockIdx.x * 64, k0 = blockIdx.y * 64;
  int t = threadIdx.x;
  int c = t & 63, r0 = t >> 6;
  for (int i = 0; i < 16; ++i) {
    int r = r0 + i * 4;
    tile[r][c] = f2bf(W[(size_t)(k0 + r) * DM + n0 + c]);
  }
  __syncthreads();
  size_t nbase = (size_t)blockIdx.z * DM + n0;
  for (int i = 0; i < 16; ++i) {
    int n = r0 + i * 4;
    Wt[(nbase + n) * DM + k0 + c] = tile[c][n];
  }
}

// ---------------- mask -> maskCb (MFMA C-layout bf16, *log2e) + zero-tile flags ----------------
__global__ void k_maskC(const float* __restrict__ mask,
                        unsigned short* __restrict__ maskCb,
                        int* __restrict__ zflags) {
  __shared__ float tile[64][65];
  __shared__ int nz;
  int q0 = blockIdx.x * 64, kv0 = blockIdx.y * 64;
  int t = threadIdx.x;
  if (t == 0) nz = 0;
  __syncthreads();
  int c = t & 63, r0 = t >> 6;
  int lnz = 0;
  for (int i = 0; i < 16; ++i) {
    int r = r0 + i * 4;
    float v = mask[(size_t)(q0 + r) * LSEQ + kv0 + c];
    tile[r][c] = v;
    lnz |= (v != 0.0f);
  }
  if (lnz) atomicOr(&nz, 1);
  __syncthreads();
  const int q = t & 63, slot = t >> 6;         // slot = tt*2 + hh
  const int tt = slot >> 1, hh = slot & 1;
  u16x8 va, vb;
#pragma unroll
  for (int r = 0; r < 8; ++r) {
    const int kvloc = 32 * tt + 4 * hh + (r & 3) + 8 * (r >> 2);
    va[r] = f2bf(tile[q][kvloc] * LOG2E);
  }
#pragma unroll
  for (int r = 8; r < 16; ++r) {
    const int kvloc = 32 * tt + 4 * hh + (r & 3) + 8 * (r >> 2);
    vb[r - 8] = f2bf(tile[q][kvloc] * LOG2E);
  }
  unsigned short* dst = maskCb + ((size_t)((kv0 >> 6) * 4 + slot) * 2048 + q0 + q) * 16;
  *reinterpret_cast<u16x8*>(dst) = va;
  *reinterpret_cast<u16x8*>(dst + 8) = vb;
  if (t == 0) zflags[blockIdx.y * 32 + blockIdx.x] = (nz == 0);
}

// ---------------- fused QKV GEMM + bias + rotary(table) + attn-tiled layouts ----------------
// qbuf:  [bh][2048][64]   (Q pre-scaled by 0.125*log2e)
// kbuf:  [bh][kv/32][c=d/16][kv&31][d&15]          (chunk stride 2048 elem)
// vtbuf: [bh][kv/16][dhalf][d&31][slot&15]         (k-permuted slots, chunk stride 1024)
__global__ __launch_bounds__(256) void k_qkv_gemm(
    const unsigned short* __restrict__ A, const unsigned short* __restrict__ Bt,
    const float* __restrict__ bq, const float* __restrict__ bk,
    const float* __restrict__ bv, const float2* __restrict__ rot,
    unsigned short* __restrict__ qbuf, unsigned short* __restrict__ kbuf,
    unsigned short* __restrict__ vtbuf) {
  __shared__ unsigned short As[128 * 32];
  __shared__ unsigned short Bs[128 * 32];
  __shared__ unsigned short otile[128 * 136];
  const int tid = threadIdx.x;
  const int lane = tid & 63, wid = tid >> 6;
  const int wm = wid >> 1, wn = wid & 1;
  const int lr = lane & 15, lg = lane >> 4;

  const int bid = blockIdx.x;
  const int xcd = bid & 7, rr = bid >> 3;
  const int mblk = xcd * 4 + (rr / 24);
  const int nblk = rr % 24;
  const int m0 = mblk * 128;
  const int n0 = nblk * 128;

  f32x4 acc[4][4] = {};

  const int e0 = tid * 8;
  const int e1 = (256 + tid) * 8;
  const int ra0 = e0 >> 5, ca0 = e0 & 31;
  const int ra1 = e1 >> 5, ca1 = e1 & 31;
  unsigned short* lA0 = As + wid * 512;
  unsigned short* lA1 = As + 2048 + wid * 512;
  unsigned short* lB0 = Bs + wid * 512;
  unsigned short* lB1 = Bs + 2048 + wid * 512;

  for (int k0 = 0; k0 < DM; k0 += 32) {
    __syncthreads();
    gld_lds16(A + (size_t)(m0 + ra0) * DM + k0 + ca0, lA0);
    gld_lds16(A + (size_t)(m0 + ra1) * DM + k0 + ca1, lA1);
    gld_lds16(Bt + (size_t)(n0 + ra0) * DM + k0 + ca0, lB0);
    gld_lds16(Bt + (size_t)(n0 + ra1) * DM + k0 + ca1, lB1);
    __syncthreads();
    bf16x8 af[4], bfv[4];
    for (int mi = 0; mi < 4; ++mi)
      af[mi] = *reinterpret_cast<const bf16x8*>(As + (wm * 64 + mi * 16 + lr) * 32 + lg * 8);
    for (int ni = 0; ni < 4; ++ni)
      bfv[ni] = *reinterpret_cast<const bf16x8*>(Bs + (wn * 64 + ni * 16 + lr) * 32 + lg * 8);
    for (int mi = 0; mi < 4; ++mi)
      for (int ni = 0; ni < 4; ++ni)
        acc[mi][ni] = __builtin_amdgcn_mfma_f32_16x16x32_bf16(af[mi], bfv[ni], acc[mi][ni], 0, 0, 0);
  }

  // ---- phase 1: bias + rotary-from-table, stage into LDS ----
  const int mat = n0 >> 10;
  const int c0 = n0 & 1023;
  const int bb = m0 >> 11;
  const int mloc = m0 & 2047;
  const float qscale = (mat == 0) ? C1SC : 1.f;
  const size_t rowbase = (size_t)(bb * LSEQ + mloc);

  for (int mi = 0; mi < 4; ++mi) {
    const int rrel_base = wm * 64 + mi * 16 + lg * 4;
    for (int ni = 0; ni < 4; ++ni) {
      const int crel = wn * 64 + ni * 16 + lr;
      const int c = (c0 + crel);
      const int d = c & 63;
      const float bias = (mat == 0 ? bq : mat == 1 ? bk : bv)[c];
      f32x4 v = acc[mi][ni];
      if (mat < 2) {
        for (int j = 0; j < 4; ++j) {
          const int rrel = rrel_base + j;
          const float x = v[j] + bias;
          const float part = __shfl_xor(x, 1, 64);
          const float2 rt = rot[(rowbase + rrel) * 64 + d];
          otile[rrel * 136 + crel] = f2bf((x * rt.x + part * rt.y) * qscale);
        }
      } else {
        for (int j = 0; j < 4; ++j) {
          const int rrel = rrel_base + j;
          otile[crel * 136 + rrel] = f2bf(v[j] + bias);
        }
      }
    }
  }
  __syncthreads();

  // ---- phase 2: coalesced 16B stores ----
  for (int i = 0; i < 2; ++i) {
    const int h = (c0 >> 6) + i;
    const size_t bh = (size_t)(bb * NH + h);
    if (mat == 0) {
      const size_t base = (bh * LSEQ + mloc) * 64;
#pragma unroll
      for (int kk2 = 0; kk2 < 4; ++kk2) {
        const int e = kk2 * 2048 + tid * 8;
        const int r = e >> 6, d = e & 63;
        *reinterpret_cast<u16x8*>(qbuf + base + e) =
            *reinterpret_cast<const u16x8*>(otile + r * 136 + i * 64 + d);
      }
    } else if (mat == 1) {
      const size_t base = bh * 131072 + (size_t)(mloc >> 5) * 2048;
#pragma unroll
      for (int kk2 = 0; kk2 < 4; ++kk2) {
        const int e = kk2 * 2048 + tid * 8;
        const int r = kk2 * 32 + ((tid >> 1) & 31);
        const int d = ((tid >> 6) & 3) * 16 + (tid & 1) * 8;
        *reinterpret_cast<u16x8*>(kbuf + base + e) =
            *reinterpret_cast<const u16x8*>(otile + r * 136 + i * 64 + d);
      }
    } else {
      const size_t base = bh * 131072 + (size_t)(mloc >> 4) * 1024;
#pragma unroll
      for (int kk2 = 0; kk2 < 4; ++kk2) {
        const int e = kk2 * 2048 + tid * 8;
        const int d = ((tid >> 6) & 1) * 32 + ((tid >> 1) & 31);
        const int rb = (kk2 * 2 + (tid >> 7)) * 16;
        const int dl = (tid & 1) * 4;
        const unsigned short* srow = otile + (i * 64 + d) * 136 + rb + dl;
        ushort4 lo = *reinterpret_cast<const ushort4*>(srow);
        ushort4 hi4 = *reinterpret_cast<const ushort4*>(srow + 8);
        u16x8 w;
        w[0] = lo.x; w[1] = lo.y; w[2] = lo.z; w[3] = lo.w;
        w[4] = hi4.x; w[5] = hi4.y; w[6] = hi4.z; w[7] = hi4.w;
        *reinterpret_cast<u16x8*>(vtbuf + base + e) = w;
      }
    }
  }
}

// ---------------- flash attention: QBLK=64/wave, kv-split x2, bh->XCD affine (r11) ----------------
__global__ __launch_bounds__(256) void k_attn(
    const unsigned short* __restrict__ qbuf, const unsigned short* __restrict__ kbuf,
    const unsigned short* __restrict__ vtbuf, const unsigned short* __restrict__ maskCb,
    const int* __restrict__ zflags, float* __restrict__ out) {
  __shared__ float obuf[2][64][68];      // [q-half][q-local][d]
  __shared__ float mlbuf[4][2][32][2];   // [wave][subtile][lane-q][m,l]
  const int tid = threadIdx.x, lane = tid & 63, wid = tid >> 6;
  const int lq = lane & 31, hi = lane >> 5;
  const int qh = wid & 1, kvh = wid >> 1;

  // bh->XCD affinity: xcd = bid&7; 4 bh per xcd; 16 q-blocks per bh
  const int bid = blockIdx.x;
  const int xcd = bid & 7, loc = bid >> 3;       // loc in [0,64)
  const int bh = xcd * 4 + (loc >> 4);
  const int qblk = loc & 15;

  const int q0 = qblk * 128 + qh * 64;
  const int qgA = q0 + lq, qgB = q0 + 32 + lq;
  const size_t bhL = (size_t)bh * LSEQ;
  const unsigned short* kb = kbuf + (size_t)bh * 131072;
  const unsigned short* vb = vtbuf + (size_t)bh * 131072;
  const unsigned short* mbA = maskCb + ((size_t)hi * 2048 + qgA) * 16;
  const unsigned short* mbB = maskCb + ((size_t)hi * 2048 + qgB) * 16;

  bf16x8 qfA[4], qfB[4];
#pragma unroll
  for (int c = 0; c < 4; ++c) {
    qfA[c] = *reinterpret_cast<const bf16x8*>(qbuf + (bhL + qgA) * 64 + c * 16 + hi * 8);
    qfB[c] = *reinterpret_cast<const bf16x8*>(qbuf + (bhL + qgB) * 64 + c * 16 + hi * 8);
  }

  f32x16 oA0 = {}, oA1 = {}, oB0 = {}, oB1 = {};
  float m2 = 2.0f, lA = 0.f, lB = 0.f;

  const int kv_beg = kvh * 1024, kv_end = kv_beg + 1024;
  for (int kv0 = kv_beg; kv0 < kv_end; kv0 += 64) {
    // mask C-init (one zflag covers the whole 64-q range of this wave)
    f32x16 sA0, sA1, sB0, sB1;
    const int zf = zflags[(kv0 >> 6) * 32 + (q0 >> 6)];
    if (zf) {
      sA0 = (f32x16){}; sA1 = (f32x16){};
      sB0 = (f32x16){}; sB1 = (f32x16){};
    } else {
      const size_t mo = (size_t)(kv0 >> 6) * (4 * 2048 * 16);
      const unsigned short* mtA = mbA + mo;
      const unsigned short* mtB = mbB + mo;
      sA0 = unpack16(*reinterpret_cast<const u16x8*>(mtA),
                     *reinterpret_cast<const u16x8*>(mtA + 8));
      sA1 = unpack16(*reinterpret_cast<const u16x8*>(mtA + 2 * 2048 * 16),
                     *reinterpret_cast<const u16x8*>(mtA + 2 * 2048 * 16 + 8));
      sB0 = unpack16(*reinterpret_cast<const u16x8*>(mtB),
                     *reinterpret_cast<const u16x8*>(mtB + 8));
      sB1 = unpack16(*reinterpret_cast<const u16x8*>(mtB + 2 * 2048 * 16),
                     *reinterpret_cast<const u16x8*>(mtB + 2 * 2048 * 16 + 8));
    }

    // S^T = K . Q^T + maskC : each K fragment feeds 2 MFMAs (subtiles A,B)
    const unsigned short* kch = kb + (size_t)(kv0 >> 5) * 2048;
#pragma unroll
    for (int c = 0; c < 4; ++c) {
      bf16x8 k0 = *reinterpret_cast<const bf16x8*>(kch + c * 512 + lq * 16 + hi * 8);
      bf16x8 k1 = *reinterpret_cast<const bf16x8*>(kch + 2048 + c * 512 + lq * 16 + hi * 8);
      sA0 = __builtin_amdgcn_mfma_f32_32x32x16_bf16(k0, qfA[c], sA0, 0, 0, 0);
      sB0 = __builtin_amdgcn_mfma_f32_32x32x16_bf16(k0, qfB[c], sB0, 0, 0, 0);
      sA1 = __builtin_amdgcn_mfma_f32_32x32x16_bf16(k1, qfA[c], sA1, 0, 0, 0);
      sB1 = __builtin_amdgcn_mfma_f32_32x32x16_bf16(k1, qfB[c], sB1, 0, 0, 0);
    }

    // V-load hoist: independent of softmax; issue now, consume ~500 cycles later
    const unsigned short* vch = vb + (size_t)(kv0 >> 4) * 1024;
    bf16x8 vf[8];
#pragma unroll
    for (int ks = 0; ks < 4; ++ks) {
      vf[2 * ks]     = *reinterpret_cast<const bf16x8*>(vch + ks * 1024 + lq * 16 + hi * 8);
      vf[2 * ks + 1] = *reinterpret_cast<const bf16x8*>(vch + ks * 1024 + 512 + lq * 16 + hi * 8);
    }

    // p = 2^(s - m2); row-sums
    float a0 = 0.f, a1 = 0.f, b0 = 0.f, b1 = 0.f;
#pragma unroll
    for (int r = 0; r < 8; ++r) {
      sA0[r] = exp2fast(sA0[r] - m2);     a0 += sA0[r];
      sA0[r + 8] = exp2fast(sA0[r + 8] - m2); a1 += sA0[r + 8];
      sB0[r] = exp2fast(sB0[r] - m2);     b0 += sB0[r];
      sB0[r + 8] = exp2fast(sB0[r + 8] - m2); b1 += sB0[r + 8];
    }
#pragma unroll
    for (int r = 0; r < 8; ++r) {
      sA1[r] = exp2fast(sA1[r] - m2);     a0 += sA1[r];
      sA1[r + 8] = exp2fast(sA1[r + 8] - m2); a1 += sA1[r + 8];
      sB1[r] = exp2fast(sB1[r] - m2);     b0 += sB1[r];
      sB1[r + 8] = exp2fast(sB1[r + 8] - m2); b1 += sB1[r + 8];
    }
    float rsA = a0 + a1, rsB = b0 + b1;

    // overflow guard: rs <= 2048 bounds P <= 2048 (rare bump path)
    if (__any(fmaxf(rsA, rsB) > 2048.f)) {
      const float cc = 0.000244140625f;   // 2^-12
#pragma unroll
      for (int r = 0; r < 16; ++r) {
        sA0[r] *= cc; sA1[r] *= cc; sB0[r] *= cc; sB1[r] *= cc;
        oA0[r] *= cc; oA1[r] *= cc; oB0[r] *= cc; oB1[r] *= cc;
      }
      rsA *= cc; rsB *= cc; lA *= cc; lB *= cc;
      m2 += 12.f;
    }

    rsA += __shfl_xor(rsA, 32, 64);
    rsB += __shfl_xor(rsB, 32, 64);
    lA += rsA; lB += rsB;

    // P -> bf16 fragments (natural order; V stored k-permuted)
    bf16x8 pfA0 = pack8(sA0, 0), pfA1 = pack8(sA0, 8);
    bf16x8 pfA2 = pack8(sA1, 0), pfA3 = pack8(sA1, 8);
    bf16x8 pfB0 = pack8(sB0, 0), pfB1 = pack8(sB0, 8);
    bf16x8 pfB2 = pack8(sB1, 0), pfB3 = pack8(sB1, 8);

    // O^T += V . P : each V fragment feeds 2 MFMAs (subtiles A,B)
#pragma unroll
    for (int ks = 0; ks < 4; ++ks) {
      bf16x8 pfA = (ks == 0) ? pfA0 : (ks == 1) ? pfA1 : (ks == 2) ? pfA2 : pfA3;
      bf16x8 pfB = (ks == 0) ? pfB0 : (ks == 1) ? pfB1 : (ks == 2) ? pfB2 : pfB3;
      oA0 = __builtin_amdgcn_mfma_f32_32x32x16_bf16(vf[2 * ks], pfA, oA0, 0, 0, 0);
      oB0 = __builtin_amdgcn_mfma_f32_32x32x16_bf16(vf[2 * ks], pfB, oB0, 0, 0, 0);
      oA1 = __builtin_amdgcn_mfma_f32_32x32x16_bf16(vf[2 * ks + 1], pfA, oA1, 0, 0, 0);
      oB1 = __builtin_amdgcn_mfma_f32_32x32x16_bf16(vf[2 * ks + 1], pfB, oB1, 0, 0, 0);
    }
  }

  // ---- merge: exchange (m,l); kvh=0 stages scaled O in LDS; kvh=1 adds + stores ----
  if (lane < 32) {
    mlbuf[wid][0][lq][0] = m2; mlbuf[wid][0][lq][1] = lA;
    mlbuf[wid][1][lq][0] = m2; mlbuf[wid][1][lq][1] = lB;
  }
  __syncthreads();
  const int pw = wid ^ 2;                     // partner wave (other kv-half)
  const float mAp = mlbuf[pw][0][lq][0], lAp = mlbuf[pw][0][lq][1];
  const float mBp = mlbuf[pw][1][lq][0], lBp = mlbuf[pw][1][lq][1];
  const float msA = fmaxf(m2, mAp);
  const float fA = exp2fast(m2 - msA), fAp = exp2fast(mAp - msA);
  const float scaleA = fA / (lA * fA + lAp * fAp);
  const float msB = fmaxf(m2, mBp);
  const float fB = exp2fast(m2 - msB), fBp = exp2fast(mBp - msB);
  const float scaleB = fB / (lB * fB + lBp * fBp);

  if (kvh == 0) {
#pragma unroll
    for (int g = 0; g < 4; ++g) {
      const int d0 = 8 * g + 4 * hi;
      float4 wA0 = make_float4(oA0[4 * g] * scaleA, oA0[4 * g + 1] * scaleA,
                               oA0[4 * g + 2] * scaleA, oA0[4 * g + 3] * scaleA);
      float4 wA1 = make_float4(oA1[4 * g] * scaleA, oA1[4 * g + 1] * scaleA,
                               oA1[4 * g + 2] * scaleA, oA1[4 * g + 3] * scaleA);
      float4 wB0 = make_float4(oB0[4 * g] * scaleB, oB0[4 * g + 1] * scaleB,
                               oB0[4 * g + 2] * scaleB, oB0[4 * g + 3] * scaleB);
      float4 wB1 = make_float4(oB1[4 * g] * scaleB, oB1[4 * g + 1] * scaleB,
                               oB1[4 * g + 2] * scaleB, oB1[4 * g + 3] * scaleB);
      *reinterpret_cast<float4*>(&obuf[qh][lq][d0])           = wA0;
      *reinterpret_cast<float4*>(&obuf[qh][lq][d0 + 32])      = wA1;
      *reinterpret_cast<float4*>(&obuf[qh][32 + lq][d0])      = wB0;
      *reinterpret_cast<float4*>(&obuf[qh][32 + lq][d0 + 32]) = wB1;
    }
  }
  __syncthreads();
  if (kvh == 1) {
    const int b = bh >> 4, h = bh & 15;
    float* orowA = out + (size_t)(b * LSEQ + qgA) * DM + h * 64;
    float* orowB = out + (size_t)(b * LSEQ + qgB) * DM + h * 64;
#pragma unroll
    for (int g = 0; g < 4; ++g) {
      const int d0 = 8 * g + 4 * hi;
      float4 pA0 = *reinterpret_cast<const float4*>(&obuf[qh][lq][d0]);
      float4 pA1 = *reinterpret_cast<const float4*>(&obuf[qh][lq][d0 + 32]);
      float4 pB0 = *reinterpret_cast<const float4*>(&obuf[qh][32 + lq][d0]);
      float4 pB1 = *reinterpret_cast<const float4*>(&obuf[qh][32 + lq][d0 + 32]);
      float4 wA0 = make_float4(pA0.x + oA0[4 * g] * scaleA, pA0.y + oA0[4 * g + 1] * scaleA,
                               pA0.z + oA0[4 * g + 2] * scaleA, pA0.w + oA0[4 * g + 3] * scaleA);
      float4 wA1 = make_float4(pA1.x + oA1[4 * g] * scaleA, pA1.y + oA1[4 * g + 1] * scaleA,
                               pA1.z + oA1[4 * g + 2] * scaleA, pA1.w + oA1[4 * g + 3] * scaleA);
      float4 wB0 = make_float4(pB0.x + oB0[4 * g] * scaleB, pB0.y + oB0[4 * g + 1] * scaleB,
                               pB0.z + oB0[4 * g + 2] * scaleB, pB0.w + oB0[4 * g + 3] * scaleB);
      float4 wB1 = make_float4(pB1.x + oB1[4 * g] * scaleB, pB1.y + oB1[4 * g + 1] * scaleB,
                               pB1.z + oB1[4 * g + 2] * scaleB, pB1.w + oB1[4 * g + 3] * scaleB);
      *reinterpret_cast<float4*>(orowA + d0)      = wA0;
      *reinterpret_cast<float4*>(orowA + d0 + 32) = wA1;
      *reinterpret_cast<float4*>(orowB + d0)      = wB0;
      *reinterpret_cast<float4*>(orowB + d0 + 32) = wB1;
    }
  }
}

extern "C" void kernel_launch(void* const* d_in, const int* in_sizes, int n_in,
                              void* d_out, int out_size, void* d_ws, size_t ws_size,
                              hipStream_t stream) {
  const float* data     = (const float*)d_in[0];
  const float* temporal = (const float*)d_in[1];
  const float* mask     = (const float*)d_in[2];
  const float* Wq       = (const float*)d_in[3];
  const float* bq       = (const float*)d_in[4];
  const float* Wk       = (const float*)d_in[5];
  const float* bk       = (const float*)d_in[6];
  const float* Wv       = (const float*)d_in[7];
  const float* bv       = (const float*)d_in[8];
  float* out = (float*)d_out;

  char* ws = (char*)d_ws;
  unsigned short* data_bf = (unsigned short*)(ws);                        // 8 MB (reused by maskCb)
  unsigned short* wt      = (unsigned short*)(ws + (size_t)8  * 1048576); // 6 MB (dead after gemm)
  unsigned short* qbuf    = (unsigned short*)(ws + (size_t)14 * 1048576); // 8 MB
  unsigned short* kbuf    = (unsigned short*)(ws + (size_t)22 * 1048576); // 8 MB
  unsigned short* vtbuf   = (unsigned short*)(ws + (size_t)30 * 1048576); // 8 MB
  unsigned short* maskCb  = data_bf;          // data_bf dead after k_qkv_gemm
  int* zflags             = (int*)wt;         // wt dead after k_qkv_gemm; 4 KB
  float2* rot             = (float2*)d_out;   // d_out dead until k_attn overwrites it (2 MB)

  hipLaunchKernelGGL(k_rotary, dim3(1024), dim3(256), 0, stream,
                     temporal, rot);
  hipLaunchKernelGGL(k_convert_data, dim3(4096), dim3(256), 0, stream,
                     data, data_bf, (2 * LSEQ * DM) / 4);
  hipLaunchKernelGGL(k_transpose_w, dim3(16, 16, 3), dim3(256), 0, stream,
                     Wq, Wk, Wv, wt);
  hipLaunchKernelGGL(k_qkv_gemm, dim3(768), dim3(256), 0, stream,
                     data_bf, wt, bq, bk, bv, rot, qbuf, kbuf, vtbuf);
  hipLaunchKernelGGL(k_maskC, dim3(32, 32), dim3(256), 0, stream,
                     mask, maskCb, zflags);
  hipLaunchKernelGGL(k_attn, dim3(512), dim3(256), 0, stream,
                     qbuf, kbuf, vtbuf, maskCb, zflags, out);
}

// Round 14
// 131.059 us; speedup vs baseline: 1.0789x; 1.0789x over previous
//
#include <hip/hip_runtime.h>
#include <hip/hip_bf16.h>

#define LSEQ 2048
#define DM   1024
#define NH   16

typedef __attribute__((ext_vector_type(8)))  short bf16x8;
typedef __attribute__((ext_vector_type(8)))  unsigned short u16x8;
typedef __attribute__((ext_vector_type(4)))  float f32x4;
typedef __attribute__((ext_vector_type(16))) float f32x16;
typedef __attribute__((ext_vector_type(4)))  unsigned int u32x4;

#define LOG2E 1.4426950408889634f
#define C1SC  0.18033688011112042f   /* 0.125 * log2(e) */

static __device__ __forceinline__ float exp2fast(float x) {
  return __builtin_amdgcn_exp2f(x);
}

static __device__ __forceinline__ unsigned short f2bf(float f) {
  unsigned int u = __float_as_uint(f);
  u += 0x7FFFu + ((u >> 16) & 1u);
  return (unsigned short)(u >> 16);
}

static __device__ __forceinline__ unsigned pk2(float a, float b) {
  __hip_bfloat162 t = __float22bfloat162_rn(make_float2(a, b));
  return *reinterpret_cast<unsigned*>(&t);
}

// unpack 16 packed bf16 (two 16B vectors) -> f32x16
static __device__ __forceinline__ f32x16 unpack16(u16x8 a, u16x8 b) {
  const u32x4 ua = __builtin_bit_cast(u32x4, a);
  const u32x4 ub = __builtin_bit_cast(u32x4, b);
  f32x16 r;
#pragma unroll
  for (int i = 0; i < 4; ++i) {
    r[2 * i]     = __uint_as_float(ua[i] << 16);
    r[2 * i + 1] = __uint_as_float(ua[i] & 0xFFFF0000u);
    r[8 + 2 * i]     = __uint_as_float(ub[i] << 16);
    r[8 + 2 * i + 1] = __uint_as_float(ub[i] & 0xFFFF0000u);
  }
  return r;
}

// pack 8 floats (natural order) -> PV B-fragment (V is k-permuted to match)
static __device__ __forceinline__ bf16x8 pack8(const f32x16& s, int base) {
  u32x4 w;
  w[0] = pk2(s[base + 0], s[base + 1]); w[1] = pk2(s[base + 2], s[base + 3]);
  w[2] = pk2(s[base + 4], s[base + 5]); w[3] = pk2(s[base + 6], s[base + 7]);
  return __builtin_bit_cast(bf16x8, w);
}

static __device__ __forceinline__ void gld_lds16(const unsigned short* g, unsigned short* l) {
  __builtin_amdgcn_global_load_lds(
      (const __attribute__((address_space(1))) unsigned int*)g,
      (__attribute__((address_space(3))) unsigned int*)l, 16, 0, 0);
}

// ---------------- fused prep: data fp32->bf16 (blocks 0..4095) + W transpose (4096..4863) ----------------
__global__ __launch_bounds__(256) void k_prep(
    const float* __restrict__ src, unsigned short* __restrict__ dst, int n4,
    const float* __restrict__ Wq, const float* __restrict__ Wk,
    const float* __restrict__ Wv, unsigned short* __restrict__ Wt) {
  __shared__ unsigned short tile[64][65];
  const int t = threadIdx.x;
  if (blockIdx.x < 4096) {
    int i = blockIdx.x * 256 + t;
    if (i >= n4) return;
    float4 v = reinterpret_cast<const float4*>(src)[i];
    ushort4 o;
    o.x = f2bf(v.x); o.y = f2bf(v.y); o.z = f2bf(v.z); o.w = f2bf(v.w);
    reinterpret_cast<ushort4*>(dst)[i] = o;
  } else {
    const int bid2 = blockIdx.x - 4096;          // 768 = 16 x 16 x 3
    const int bz = bid2 >> 8, rem = bid2 & 255;
    const int by = rem >> 4, bx = rem & 15;
    const float* W = (bz == 0) ? Wq : (bz == 1) ? Wk : Wv;
    int n0 = bx * 64, k0 = by * 64;
    int c = t & 63, r0 = t >> 6;
    for (int i = 0; i < 16; ++i) {
      int r = r0 + i * 4;
      tile[r][c] = f2bf(W[(size_t)(k0 + r) * DM + n0 + c]);
    }
    __syncthreads();
    size_t nbase = (size_t)bz * DM + n0;
    for (int i = 0; i < 16; ++i) {
      int n = r0 + i * 4;
      Wt[(nbase + n) * DM + k0 + c] = tile[c][n];
    }
  }
}

// ---------------- mask -> maskCb (MFMA C-layout bf16, *log2e) + zero-tile flags ----------------
__global__ void k_maskC(const float* __restrict__ mask,
                        unsigned short* __restrict__ maskCb,
                        int* __restrict__ zflags) {
  __shared__ float tile[64][65];
  __shared__ int nz;
  int q0 = blockIdx.x * 64, kv0 = blockIdx.y * 64;
  int t = threadIdx.x;
  if (t == 0) nz = 0;
  __syncthreads();
  int c = t & 63, r0 = t >> 6;
  int lnz = 0;
  for (int i = 0; i < 16; ++i) {
    int r = r0 + i * 4;
    float v = mask[(size_t)(q0 + r) * LSEQ + kv0 + c];
    tile[r][c] = v;
    lnz |= (v != 0.0f);
  }
  if (lnz) atomicOr(&nz, 1);
  __syncthreads();
  const int q = t & 63, slot = t >> 6;         // slot = tt*2 + hh
  const int tt = slot >> 1, hh = slot & 1;
  u16x8 va, vb;
#pragma unroll
  for (int r = 0; r < 8; ++r) {
    const int kvloc = 32 * tt + 4 * hh + (r & 3) + 8 * (r >> 2);
    va[r] = f2bf(tile[q][kvloc] * LOG2E);
  }
#pragma unroll
  for (int r = 8; r < 16; ++r) {
    const int kvloc = 32 * tt + 4 * hh + (r & 3) + 8 * (r >> 2);
    vb[r - 8] = f2bf(tile[q][kvloc] * LOG2E);
  }
  unsigned short* dst = maskCb + ((size_t)((kv0 >> 6) * 4 + slot) * 2048 + q0 + q) * 16;
  *reinterpret_cast<u16x8*>(dst) = va;
  *reinterpret_cast<u16x8*>(dst + 8) = vb;
  if (t == 0) zflags[blockIdx.y * 32 + blockIdx.x] = (nz == 0);
}

// ---------------- fused QKV GEMM + bias + rotary (+Q pre-scale) + attn-tiled layouts ----------------
// qbuf:  [bh][2048][64]   (Q pre-scaled by 0.125*log2e)
// kbuf:  [bh][kv/32][c=d/16][kv&31][d&15]          (chunk stride 2048 elem)
// vtbuf: [bh][kv/16][dhalf][d&31][slot&15]         (k-permuted slots, chunk stride 1024)
__global__ __launch_bounds__(256) void k_qkv_gemm(
    const unsigned short* __restrict__ A, const unsigned short* __restrict__ Bt,
    const float* __restrict__ bq, const float* __restrict__ bk,
    const float* __restrict__ bv, const float* __restrict__ temporal,
    unsigned short* __restrict__ qbuf, unsigned short* __restrict__ kbuf,
    unsigned short* __restrict__ vtbuf) {
  __shared__ unsigned short As[128 * 32];
  __shared__ unsigned short Bs[128 * 32];
  __shared__ unsigned short otile[128 * 136];
  const int tid = threadIdx.x;
  const int lane = tid & 63, wid = tid >> 6;
  const int wm = wid >> 1, wn = wid & 1;
  const int lr = lane & 15, lg = lane >> 4;

  const int bid = blockIdx.x;
  const int xcd = bid & 7, rr = bid >> 3;
  const int mblk = xcd * 4 + (rr / 24);
  const int nblk = rr % 24;
  const int m0 = mblk * 128;
  const int n0 = nblk * 128;

  f32x4 acc[4][4] = {};

  const int e0 = tid * 8;
  const int e1 = (256 + tid) * 8;
  const int ra0 = e0 >> 5, ca0 = e0 & 31;
  const int ra1 = e1 >> 5, ca1 = e1 & 31;
  unsigned short* lA0 = As + wid * 512;
  unsigned short* lA1 = As + 2048 + wid * 512;
  unsigned short* lB0 = Bs + wid * 512;
  unsigned short* lB1 = Bs + 2048 + wid * 512;

  for (int k0 = 0; k0 < DM; k0 += 32) {
    __syncthreads();
    gld_lds16(A + (size_t)(m0 + ra0) * DM + k0 + ca0, lA0);
    gld_lds16(A + (size_t)(m0 + ra1) * DM + k0 + ca1, lA1);
    gld_lds16(Bt + (size_t)(n0 + ra0) * DM + k0 + ca0, lB0);
    gld_lds16(Bt + (size_t)(n0 + ra1) * DM + k0 + ca1, lB1);
    __syncthreads();
    bf16x8 af[4], bfv[4];
    for (int mi = 0; mi < 4; ++mi)
      af[mi] = *reinterpret_cast<const bf16x8*>(As + (wm * 64 + mi * 16 + lr) * 32 + lg * 8);
    for (int ni = 0; ni < 4; ++ni)
      bfv[ni] = *reinterpret_cast<const bf16x8*>(Bs + (wn * 64 + ni * 16 + lr) * 32 + lg * 8);
    for (int mi = 0; mi < 4; ++mi)
      for (int ni = 0; ni < 4; ++ni)
        acc[mi][ni] = __builtin_amdgcn_mfma_f32_16x16x32_bf16(af[mi], bfv[ni], acc[mi][ni], 0, 0, 0);
  }

  // ---- phase 1: bias/rotary, stage into LDS ----
  const int mat = n0 >> 10;
  const int c0 = n0 & 1023;
  const int bb = m0 >> 11;
  const int mloc = m0 & 2047;
  const float qscale = (mat == 0) ? C1SC : 1.f;

  for (int mi = 0; mi < 4; ++mi) {
    const int rrel_base = wm * 64 + mi * 16 + lg * 4;
    for (int ni = 0; ni < 4; ++ni) {
      const int crel = wn * 64 + ni * 16 + lr;
      const int c = (c0 + crel);
      const int d = c & 63;
      const float bias = (mat == 0 ? bq : mat == 1 ? bk : bv)[c];
      f32x4 v = acc[mi][ni];
      if (mat < 2) {
        const int jj = d & 15, tt = d >> 4;
        const float fr = __expf(-(float)(jj & 14) * 0.5756462732485115f);
        const float sign = (d & 1) ? 1.f : -1.f;
        for (int j = 0; j < 4; ++j) {
          const int rrel = rrel_base + j;
          const float x = v[j] + bias;
          const float part = __shfl_xor(x, 1, 64);
          const int lqs = mloc + rrel;
          const float fq = temporal[((size_t)bb * LSEQ + lqs) * 4 + tt] * fr;
          float sn, cs;
          __sincosf(fq, &sn, &cs);
          otile[rrel * 136 + crel] = f2bf((x * cs + sign * part * sn) * qscale);
        }
      } else {
        for (int j = 0; j < 4; ++j) {
          const int rrel = rrel_base + j;
          otile[crel * 136 + rrel] = f2bf(v[j] + bias);
        }
      }
    }
  }
  __syncthreads();

  // ---- phase 2: coalesced 16B stores ----
  for (int i = 0; i < 2; ++i) {
    const int h = (c0 >> 6) + i;
    const size_t bh = (size_t)(bb * NH + h);
    if (mat == 0) {
      const size_t base = (bh * LSEQ + mloc) * 64;
#pragma unroll
      for (int kk2 = 0; kk2 < 4; ++kk2) {
        const int e = kk2 * 2048 + tid * 8;
        const int r = e >> 6, d = e & 63;
        *reinterpret_cast<u16x8*>(qbuf + base + e) =
            *reinterpret_cast<const u16x8*>(otile + r * 136 + i * 64 + d);
      }
    } else if (mat == 1) {
      const size_t base = bh * 131072 + (size_t)(mloc >> 5) * 2048;
#pragma unroll
      for (int kk2 = 0; kk2 < 4; ++kk2) {
        const int e = kk2 * 2048 + tid * 8;
        const int r = kk2 * 32 + ((tid >> 1) & 31);
        const int d = ((tid >> 6) & 3) * 16 + (tid & 1) * 8;
        *reinterpret_cast<u16x8*>(kbuf + base + e) =
            *reinterpret_cast<const u16x8*>(otile + r * 136 + i * 64 + d);
      }
    } else {
      const size_t base = bh * 131072 + (size_t)(mloc >> 4) * 1024;
#pragma unroll
      for (int kk2 = 0; kk2 < 4; ++kk2) {
        const int e = kk2 * 2048 + tid * 8;
        const int d = ((tid >> 6) & 1) * 32 + ((tid >> 1) & 31);
        const int rb = (kk2 * 2 + (tid >> 7)) * 16;
        const int dl = (tid & 1) * 4;
        const unsigned short* srow = otile + (i * 64 + d) * 136 + rb + dl;
        ushort4 lo = *reinterpret_cast<const ushort4*>(srow);
        ushort4 hi4 = *reinterpret_cast<const ushort4*>(srow + 8);
        u16x8 w;
        w[0] = lo.x; w[1] = lo.y; w[2] = lo.z; w[3] = lo.w;
        w[4] = hi4.x; w[5] = hi4.y; w[6] = hi4.z; w[7] = hi4.w;
        *reinterpret_cast<u16x8*>(vtbuf + base + e) = w;
      }
    }
  }
}

// ---------------- flash attention: QBLK=64/wave, kv-split x2, bh->XCD affine (r11) ----------------
__global__ __launch_bounds__(256) void k_attn(
    const unsigned short* __restrict__ qbuf, const unsigned short* __restrict__ kbuf,
    const unsigned short* __restrict__ vtbuf, const unsigned short* __restrict__ maskCb,
    const int* __restrict__ zflags, float* __restrict__ out) {
  __shared__ float obuf[2][64][68];      // [q-half][q-local][d]
  __shared__ float mlbuf[4][2][32][2];   // [wave][subtile][lane-q][m,l]
  const int tid = threadIdx.x, lane = tid & 63, wid = tid >> 6;
  const int lq = lane & 31, hi = lane >> 5;
  const int qh = wid & 1, kvh = wid >> 1;

  // bh->XCD affinity: xcd = bid&7; 4 bh per xcd; 16 q-blocks per bh
  const int bid = blockIdx.x;
  const int xcd = bid & 7, loc = bid >> 3;       // loc in [0,64)
  const int bh = xcd * 4 + (loc >> 4);
  const int qblk = loc & 15;

  const int q0 = qblk * 128 + qh * 64;
  const int qgA = q0 + lq, qgB = q0 + 32 + lq;
  const size_t bhL = (size_t)bh * LSEQ;
  const unsigned short* kb = kbuf + (size_t)bh * 131072;
  const unsigned short* vb = vtbuf + (size_t)bh * 131072;
  const unsigned short* mbA = maskCb + ((size_t)hi * 2048 + qgA) * 16;
  const unsigned short* mbB = maskCb + ((size_t)hi * 2048 + qgB) * 16;

  bf16x8 qfA[4], qfB[4];
#pragma unroll
  for (int c = 0; c < 4; ++c) {
    qfA[c] = *reinterpret_cast<const bf16x8*>(qbuf + (bhL + qgA) * 64 + c * 16 + hi * 8);
    qfB[c] = *reinterpret_cast<const bf16x8*>(qbuf + (bhL + qgB) * 64 + c * 16 + hi * 8);
  }

  f32x16 oA0 = {}, oA1 = {}, oB0 = {}, oB1 = {};
  float m2 = 2.0f, lA = 0.f, lB = 0.f;

  const int kv_beg = kvh * 1024, kv_end = kv_beg + 1024;
  for (int kv0 = kv_beg; kv0 < kv_end; kv0 += 64) {
    // mask C-init (one zflag covers the whole 64-q range of this wave)
    f32x16 sA0, sA1, sB0, sB1;
    const int zf = zflags[(kv0 >> 6) * 32 + (q0 >> 6)];
    if (zf) {
      sA0 = (f32x16){}; sA1 = (f32x16){};
      sB0 = (f32x16){}; sB1 = (f32x16){};
    } else {
      const size_t mo = (size_t)(kv0 >> 6) * (4 * 2048 * 16);
      const unsigned short* mtA = mbA + mo;
      const unsigned short* mtB = mbB + mo;
      sA0 = unpack16(*reinterpret_cast<const u16x8*>(mtA),
                     *reinterpret_cast<const u16x8*>(mtA + 8));
      sA1 = unpack16(*reinterpret_cast<const u16x8*>(mtA + 2 * 2048 * 16),
                     *reinterpret_cast<const u16x8*>(mtA + 2 * 2048 * 16 + 8));
      sB0 = unpack16(*reinterpret_cast<const u16x8*>(mtB),
                     *reinterpret_cast<const u16x8*>(mtB + 8));
      sB1 = unpack16(*reinterpret_cast<const u16x8*>(mtB + 2 * 2048 * 16),
                     *reinterpret_cast<const u16x8*>(mtB + 2 * 2048 * 16 + 8));
    }

    // S^T = K . Q^T + maskC : each K fragment feeds 2 MFMAs (subtiles A,B)
    const unsigned short* kch = kb + (size_t)(kv0 >> 5) * 2048;
#pragma unroll
    for (int c = 0; c < 4; ++c) {
      bf16x8 k0 = *reinterpret_cast<const bf16x8*>(kch + c * 512 + lq * 16 + hi * 8);
      bf16x8 k1 = *reinterpret_cast<const bf16x8*>(kch + 2048 + c * 512 + lq * 16 + hi * 8);
      sA0 = __builtin_amdgcn_mfma_f32_32x32x16_bf16(k0, qfA[c], sA0, 0, 0, 0);
      sB0 = __builtin_amdgcn_mfma_f32_32x32x16_bf16(k0, qfB[c], sB0, 0, 0, 0);
      sA1 = __builtin_amdgcn_mfma_f32_32x32x16_bf16(k1, qfA[c], sA1, 0, 0, 0);
      sB1 = __builtin_amdgcn_mfma_f32_32x32x16_bf16(k1, qfB[c], sB1, 0, 0, 0);
    }

    // V-load hoist: independent of softmax; issue now, consume ~500 cycles later
    const unsigned short* vch = vb + (size_t)(kv0 >> 4) * 1024;
    bf16x8 vf[8];
#pragma unroll
    for (int ks = 0; ks < 4; ++ks) {
      vf[2 * ks]     = *reinterpret_cast<const bf16x8*>(vch + ks * 1024 + lq * 16 + hi * 8);
      vf[2 * ks + 1] = *reinterpret_cast<const bf16x8*>(vch + ks * 1024 + 512 + lq * 16 + hi * 8);
    }

    // p = 2^(s - m2); row-sums
    float a0 = 0.f, a1 = 0.f, b0 = 0.f, b1 = 0.f;
#pragma unroll
    for (int r = 0; r < 8; ++r) {
      sA0[r] = exp2fast(sA0[r] - m2);     a0 += sA0[r];
      sA0[r + 8] = exp2fast(sA0[r + 8] - m2); a1 += sA0[r + 8];
      sB0[r] = exp2fast(sB0[r] - m2);     b0 += sB0[r];
      sB0[r + 8] = exp2fast(sB0[r + 8] - m2); b1 += sB0[r + 8];
    }
#pragma unroll
    for (int r = 0; r < 8; ++r) {
      sA1[r] = exp2fast(sA1[r] - m2);     a0 += sA1[r];
      sA1[r + 8] = exp2fast(sA1[r + 8] - m2); a1 += sA1[r + 8];
      sB1[r] = exp2fast(sB1[r] - m2);     b0 += sB1[r];
      sB1[r + 8] = exp2fast(sB1[r + 8] - m2); b1 += sB1[r + 8];
    }
    float rsA = a0 + a1, rsB = b0 + b1;

    // overflow guard: rs <= 2048 bounds P <= 2048 (rare bump path)
    if (__any(fmaxf(rsA, rsB) > 2048.f)) {
      const float cc = 0.000244140625f;   // 2^-12
#pragma unroll
      for (int r = 0; r < 16; ++r) {
        sA0[r] *= cc; sA1[r] *= cc; sB0[r] *= cc; sB1[r] *= cc;
        oA0[r] *= cc; oA1[r] *= cc; oB0[r] *= cc; oB1[r] *= cc;
      }
      rsA *= cc; rsB *= cc; lA *= cc; lB *= cc;
      m2 += 12.f;
    }

    rsA += __shfl_xor(rsA, 32, 64);
    rsB += __shfl_xor(rsB, 32, 64);
    lA += rsA; lB += rsB;

    // P -> bf16 fragments (natural order; V stored k-permuted)
    bf16x8 pfA0 = pack8(sA0, 0), pfA1 = pack8(sA0, 8);
    bf16x8 pfA2 = pack8(sA1, 0), pfA3 = pack8(sA1, 8);
    bf16x8 pfB0 = pack8(sB0, 0), pfB1 = pack8(sB0, 8);
    bf16x8 pfB2 = pack8(sB1, 0), pfB3 = pack8(sB1, 8);

    // O^T += V . P : each V fragment feeds 2 MFMAs (subtiles A,B)
#pragma unroll
    for (int ks = 0; ks < 4; ++ks) {
      bf16x8 pfA = (ks == 0) ? pfA0 : (ks == 1) ? pfA1 : (ks == 2) ? pfA2 : pfA3;
      bf16x8 pfB = (ks == 0) ? pfB0 : (ks == 1) ? pfB1 : (ks == 2) ? pfB2 : pfB3;
      oA0 = __builtin_amdgcn_mfma_f32_32x32x16_bf16(vf[2 * ks], pfA, oA0, 0, 0, 0);
      oB0 = __builtin_amdgcn_mfma_f32_32x32x16_bf16(vf[2 * ks], pfB, oB0, 0, 0, 0);
      oA1 = __builtin_amdgcn_mfma_f32_32x32x16_bf16(vf[2 * ks + 1], pfA, oA1, 0, 0, 0);
      oB1 = __builtin_amdgcn_mfma_f32_32x32x16_bf16(vf[2 * ks + 1], pfB, oB1, 0, 0, 0);
    }
  }

  // ---- merge: exchange (m,l); kvh=0 stages scaled O in LDS; kvh=1 adds + stores ----
  if (lane < 32) {
    mlbuf[wid][0][lq][0] = m2; mlbuf[wid][0][lq][1] = lA;
    mlbuf[wid][1][lq][0] = m2; mlbuf[wid][1][lq][1] = lB;
  }
  __syncthreads();
  const int pw = wid ^ 2;                     // partner wave (other kv-half)
  const float mAp = mlbuf[pw][0][lq][0], lAp = mlbuf[pw][0][lq][1];
  const float mBp = mlbuf[pw][1][lq][0], lBp = mlbuf[pw][1][lq][1];
  const float msA = fmaxf(m2, mAp);
  const float fA = exp2fast(m2 - msA), fAp = exp2fast(mAp - msA);
  const float scaleA = fA / (lA * fA + lAp * fAp);
  const float msB = fmaxf(m2, mBp);
  const float fB = exp2fast(m2 - msB), fBp = exp2fast(mBp - msB);
  const float scaleB = fB / (lB * fB + lBp * fBp);

  if (kvh == 0) {
#pragma unroll
    for (int g = 0; g < 4; ++g) {
      const int d0 = 8 * g + 4 * hi;
      float4 wA0 = make_float4(oA0[4 * g] * scaleA, oA0[4 * g + 1] * scaleA,
                               oA0[4 * g + 2] * scaleA, oA0[4 * g + 3] * scaleA);
      float4 wA1 = make_float4(oA1[4 * g] * scaleA, oA1[4 * g + 1] * scaleA,
                               oA1[4 * g + 2] * scaleA, oA1[4 * g + 3] * scaleA);
      float4 wB0 = make_float4(oB0[4 * g] * scaleB, oB0[4 * g + 1] * scaleB,
                               oB0[4 * g + 2] * scaleB, oB0[4 * g + 3] * scaleB);
      float4 wB1 = make_float4(oB1[4 * g] * scaleB, oB1[4 * g + 1] * scaleB,
                               oB1[4 * g + 2] * scaleB, oB1[4 * g + 3] * scaleB);
      *reinterpret_cast<float4*>(&obuf[qh][lq][d0])           = wA0;
      *reinterpret_cast<float4*>(&obuf[qh][lq][d0 + 32])      = wA1;
      *reinterpret_cast<float4*>(&obuf[qh][32 + lq][d0])      = wB0;
      *reinterpret_cast<float4*>(&obuf[qh][32 + lq][d0 + 32]) = wB1;
    }
  }
  __syncthreads();
  if (kvh == 1) {
    const int b = bh >> 4, h = bh & 15;
    float* orowA = out + (size_t)(b * LSEQ + qgA) * DM + h * 64;
    float* orowB = out + (size_t)(b * LSEQ + qgB) * DM + h * 64;
#pragma unroll
    for (int g = 0; g < 4; ++g) {
      const int d0 = 8 * g + 4 * hi;
      float4 pA0 = *reinterpret_cast<const float4*>(&obuf[qh][lq][d0]);
      float4 pA1 = *reinterpret_cast<const float4*>(&obuf[qh][lq][d0 + 32]);
      float4 pB0 = *reinterpret_cast<const float4*>(&obuf[qh][32 + lq][d0]);
      float4 pB1 = *reinterpret_cast<const float4*>(&obuf[qh][32 + lq][d0 + 32]);
      float4 wA0 = make_float4(pA0.x + oA0[4 * g] * scaleA, pA0.y + oA0[4 * g + 1] * scaleA,
                               pA0.z + oA0[4 * g + 2] * scaleA, pA0.w + oA0[4 * g + 3] * scaleA);
      float4 wA1 = make_float4(pA1.x + oA1[4 * g] * scaleA, pA1.y + oA1[4 * g + 1] * scaleA,
                               pA1.z + oA1[4 * g + 2] * scaleA, pA1.w + oA1[4 * g + 3] * scaleA);
      float4 wB0 = make_float4(pB0.x + oB0[4 * g] * scaleB, pB0.y + oB0[4 * g + 1] * scaleB,
                               pB0.z + oB0[4 * g + 2] * scaleB, pB0.w + oB0[4 * g + 3] * scaleB);
      float4 wB1 = make_float4(pB1.x + oB1[4 * g] * scaleB, pB1.y + oB1[4 * g + 1] * scaleB,
                               pB1.z + oB1[4 * g + 2] * scaleB, pB1.w + oB1[4 * g + 3] * scaleB);
      *reinterpret_cast<float4*>(orowA + d0)      = wA0;
      *reinterpret_cast<float4*>(orowA + d0 + 32) = wA1;
      *reinterpret_cast<float4*>(orowB + d0)      = wB0;
      *reinterpret_cast<float4*>(orowB + d0 + 32) = wB1;
    }
  }
}

extern "C" void kernel_launch(void* const* d_in, const int* in_sizes, int n_in,
                              void* d_out, int out_size, void* d_ws, size_t ws_size,
                              hipStream_t stream) {
  const float* data     = (const float*)d_in[0];
  const float* temporal = (const float*)d_in[1];
  const float* mask     = (const float*)d_in[2];
  const float* Wq       = (const float*)d_in[3];
  const float* bq       = (const float*)d_in[4];
  const float* Wk       = (const float*)d_in[5];
  const float* bk       = (const float*)d_in[6];
  const float* Wv       = (const float*)d_in[7];
  const float* bv       = (const float*)d_in[8];
  float* out = (float*)d_out;

  char* ws = (char*)d_ws;
  unsigned short* data_bf = (unsigned short*)(ws);                        // 8 MB (reused by maskCb)
  unsigned short* wt      = (unsigned short*)(ws + (size_t)8  * 1048576); // 6 MB (dead after gemm)
  unsigned short* qbuf    = (unsigned short*)(ws + (size_t)14 * 1048576); // 8 MB
  unsigned short* kbuf    = (unsigned short*)(ws + (size_t)22 * 1048576); // 8 MB
  unsigned short* vtbuf   = (unsigned short*)(ws + (size_t)30 * 1048576); // 8 MB
  unsigned short* maskCb  = data_bf;          // data_bf dead after k_qkv_gemm
  int* zflags             = (int*)wt;         // wt dead after k_qkv_gemm; 4 KB

  hipLaunchKernelGGL(k_prep, dim3(4096 + 768), dim3(256), 0, stream,
                     data, data_bf, (2 * LSEQ * DM) / 4, Wq, Wk, Wv, wt);
  hipLaunchKernelGGL(k_qkv_gemm, dim3(768), dim3(256), 0, stream,
                     data_bf, wt, bq, bk, bv, temporal, qbuf, kbuf, vtbuf);
  hipLaunchKernelGGL(k_maskC, dim3(32, 32), dim3(256), 0, stream,
                     mask, maskCb, zflags);
  hipLaunchKernelGGL(k_attn, dim3(512), dim3(256), 0, stream,
                     qbuf, kbuf, vtbuf, maskCb, zflags, out);
}

// Round 15
// 126.563 us; speedup vs baseline: 1.1172x; 1.0355x over previous
//
#include <hip/hip_runtime.h>
#include <hip/hip_bf16.h>

#define LSEQ 2048
#define DM   1024
#define NH   16

typedef __attribute__((ext_vector_type(8)))  short bf16x8;
typedef __attribute__((ext_vector_type(8)))  unsigned short u16x8;
typedef __attribute__((ext_vector_type(4)))  float f32x4;
typedef __attribute__((ext_vector_type(16))) float f32x16;
typedef __attribute__((ext_vector_type(4)))  unsigned int u32x4;

#define LOG2E 1.4426950408889634f
#define C1SC  0.18033688011112042f   /* 0.125 * log2(e) */

static __device__ __forceinline__ float exp2fast(float x) {
  return __builtin_amdgcn_exp2f(x);
}

static __device__ __forceinline__ unsigned short f2bf(float f) {
  unsigned int u = __float_as_uint(f);
  u += 0x7FFFu + ((u >> 16) & 1u);
  return (unsigned short)(u >> 16);
}

static __device__ __forceinline__ unsigned pk2(float a, float b) {
  __hip_bfloat162 t = __float22bfloat162_rn(make_float2(a, b));
  return *reinterpret_cast<unsigned*>(&t);
}

// unpack 16 packed bf16 (two 16B vectors) -> f32x16
static __device__ __forceinline__ f32x16 unpack16(u16x8 a, u16x8 b) {
  const u32x4 ua = __builtin_bit_cast(u32x4, a);
  const u32x4 ub = __builtin_bit_cast(u32x4, b);
  f32x16 r;
#pragma unroll
  for (int i = 0; i < 4; ++i) {
    r[2 * i]     = __uint_as_float(ua[i] << 16);
    r[2 * i + 1] = __uint_as_float(ua[i] & 0xFFFF0000u);
    r[8 + 2 * i]     = __uint_as_float(ub[i] << 16);
    r[8 + 2 * i + 1] = __uint_as_float(ub[i] & 0xFFFF0000u);
  }
  return r;
}

// pack 8 floats (natural order) -> PV B-fragment (V is k-permuted to match)
static __device__ __forceinline__ bf16x8 pack8(const f32x16& s, int base) {
  u32x4 w;
  w[0] = pk2(s[base + 0], s[base + 1]); w[1] = pk2(s[base + 2], s[base + 3]);
  w[2] = pk2(s[base + 4], s[base + 5]); w[3] = pk2(s[base + 6], s[base + 7]);
  return __builtin_bit_cast(bf16x8, w);
}

static __device__ __forceinline__ void gld_lds16(const unsigned short* g, unsigned short* l) {
  __builtin_amdgcn_global_load_lds(
      (const __attribute__((address_space(1))) unsigned int*)g,
      (__attribute__((address_space(3))) unsigned int*)l, 16, 0, 0);
}

// ---------------- fused prep: data fp32->bf16 (blocks 0..4095) + W transpose (4096..4863) ----------------
__global__ __launch_bounds__(256) void k_prep(
    const float* __restrict__ src, unsigned short* __restrict__ dst, int n4,
    const float* __restrict__ Wq, const float* __restrict__ Wk,
    const float* __restrict__ Wv, unsigned short* __restrict__ Wt) {
  __shared__ unsigned short tile[64][65];
  const int t = threadIdx.x;
  if (blockIdx.x < 4096) {
    int i = blockIdx.x * 256 + t;
    if (i >= n4) return;
    float4 v = reinterpret_cast<const float4*>(src)[i];
    ushort4 o;
    o.x = f2bf(v.x); o.y = f2bf(v.y); o.z = f2bf(v.z); o.w = f2bf(v.w);
    reinterpret_cast<ushort4*>(dst)[i] = o;
  } else {
    const int bid2 = blockIdx.x - 4096;          // 768 = 16 x 16 x 3
    const int bz = bid2 >> 8, rem = bid2 & 255;
    const int by = rem >> 4, bx = rem & 15;
    const float* W = (bz == 0) ? Wq : (bz == 1) ? Wk : Wv;
    int n0 = bx * 64, k0 = by * 64;
    int c = t & 63, r0 = t >> 6;
    for (int i = 0; i < 16; ++i) {
      int r = r0 + i * 4;
      tile[r][c] = f2bf(W[(size_t)(k0 + r) * DM + n0 + c]);
    }
    __syncthreads();
    size_t nbase = (size_t)bz * DM + n0;
    for (int i = 0; i < 16; ++i) {
      int n = r0 + i * 4;
      Wt[(nbase + n) * DM + k0 + c] = tile[c][n];
    }
  }
}

// ---------------- fused QKV GEMM (blocks 0..767) + maskC prep (768..1791) ----------------
// qbuf:  [bh][2048][64]   (Q pre-scaled by 0.125*log2e)
// kbuf:  [bh][kv/32][c=d/16][kv&31][d&15]          (chunk stride 2048 elem)
// vtbuf: [bh][kv/16][dhalf][d&31][slot&15]         (k-permuted slots, chunk stride 1024)
// maskCb[((kv0/64)*4 + t*2 + hi) * 2048 + q][16]: r -> kv_local = 32t+4hi+(r&3)+8(r>>2)
// zflags[kvblk*32 + qblk] = 1 iff 64x64 tile all-zero. maskC is independent of the GEMM,
// so its blocks fill the GEMM dispatch's scheduling gaps/tail.
__global__ __launch_bounds__(256) void k_qkv_gemm(
    const unsigned short* __restrict__ A, const unsigned short* __restrict__ Bt,
    const float* __restrict__ bq, const float* __restrict__ bk,
    const float* __restrict__ bv, const float* __restrict__ temporal,
    unsigned short* __restrict__ qbuf, unsigned short* __restrict__ kbuf,
    unsigned short* __restrict__ vtbuf,
    const float* __restrict__ mask, unsigned short* __restrict__ maskCb,
    int* __restrict__ zflags) {
  __shared__ unsigned short As[128 * 32];
  __shared__ unsigned short Bs[128 * 32];
  __shared__ unsigned short otile[128 * 136];    // also aliased as maskC's float tile
  __shared__ int nz;
  const int tid = threadIdx.x;

  if (blockIdx.x >= 768) {
    // ---------------- maskC path (blocks 768..1791) ----------------
    float (*tile)[65] = reinterpret_cast<float(*)[65]>(otile);  // 16.6KB carved from otile
    const int bid2 = blockIdx.x - 768;           // 1024 = 32 qblk x 32 kvblk
    const int qblk = bid2 & 31, kvblk = bid2 >> 5;
    const int q0 = qblk * 64, kv0 = kvblk * 64;
    const int t = tid;
    if (t == 0) nz = 0;
    __syncthreads();
    int c = t & 63, r0 = t >> 6;
    int lnz = 0;
    for (int i = 0; i < 16; ++i) {
      int r = r0 + i * 4;
      float v = mask[(size_t)(q0 + r) * LSEQ + kv0 + c];
      tile[r][c] = v;
      lnz |= (v != 0.0f);
    }
    if (lnz) atomicOr(&nz, 1);
    __syncthreads();
    const int q = t & 63, slot = t >> 6;         // slot = tt*2 + hh
    const int tt = slot >> 1, hh = slot & 1;
    u16x8 va, vb;
#pragma unroll
    for (int r = 0; r < 8; ++r) {
      const int kvloc = 32 * tt + 4 * hh + (r & 3) + 8 * (r >> 2);
      va[r] = f2bf(tile[q][kvloc] * LOG2E);
    }
#pragma unroll
    for (int r = 8; r < 16; ++r) {
      const int kvloc = 32 * tt + 4 * hh + (r & 3) + 8 * (r >> 2);
      vb[r - 8] = f2bf(tile[q][kvloc] * LOG2E);
    }
    unsigned short* dst = maskCb + ((size_t)((kv0 >> 6) * 4 + slot) * 2048 + q0 + q) * 16;
    *reinterpret_cast<u16x8*>(dst) = va;
    *reinterpret_cast<u16x8*>(dst + 8) = vb;
    if (t == 0) zflags[kvblk * 32 + qblk] = (nz == 0);
    return;
  }

  // ---------------- GEMM path (blocks 0..767) ----------------
  const int lane = tid & 63, wid = tid >> 6;
  const int wm = wid >> 1, wn = wid & 1;
  const int lr = lane & 15, lg = lane >> 4;

  const int bid = blockIdx.x;
  const int xcd = bid & 7, rr = bid >> 3;
  const int mblk = xcd * 4 + (rr / 24);
  const int nblk = rr % 24;
  const int m0 = mblk * 128;
  const int n0 = nblk * 128;

  f32x4 acc[4][4] = {};

  const int e0 = tid * 8;
  const int e1 = (256 + tid) * 8;
  const int ra0 = e0 >> 5, ca0 = e0 & 31;
  const int ra1 = e1 >> 5, ca1 = e1 & 31;
  unsigned short* lA0 = As + wid * 512;
  unsigned short* lA1 = As + 2048 + wid * 512;
  unsigned short* lB0 = Bs + wid * 512;
  unsigned short* lB1 = Bs + 2048 + wid * 512;

  for (int k0 = 0; k0 < DM; k0 += 32) {
    __syncthreads();
    gld_lds16(A + (size_t)(m0 + ra0) * DM + k0 + ca0, lA0);
    gld_lds16(A + (size_t)(m0 + ra1) * DM + k0 + ca1, lA1);
    gld_lds16(Bt + (size_t)(n0 + ra0) * DM + k0 + ca0, lB0);
    gld_lds16(Bt + (size_t)(n0 + ra1) * DM + k0 + ca1, lB1);
    __syncthreads();
    bf16x8 af[4], bfv[4];
    for (int mi = 0; mi < 4; ++mi)
      af[mi] = *reinterpret_cast<const bf16x8*>(As + (wm * 64 + mi * 16 + lr) * 32 + lg * 8);
    for (int ni = 0; ni < 4; ++ni)
      bfv[ni] = *reinterpret_cast<const bf16x8*>(Bs + (wn * 64 + ni * 16 + lr) * 32 + lg * 8);
    for (int mi = 0; mi < 4; ++mi)
      for (int ni = 0; ni < 4; ++ni)
        acc[mi][ni] = __builtin_amdgcn_mfma_f32_16x16x32_bf16(af[mi], bfv[ni], acc[mi][ni], 0, 0, 0);
  }

  // ---- phase 1: bias/rotary, stage into LDS ----
  const int mat = n0 >> 10;
  const int c0 = n0 & 1023;
  const int bb = m0 >> 11;
  const int mloc = m0 & 2047;
  const float qscale = (mat == 0) ? C1SC : 1.f;

  for (int mi = 0; mi < 4; ++mi) {
    const int rrel_base = wm * 64 + mi * 16 + lg * 4;
    for (int ni = 0; ni < 4; ++ni) {
      const int crel = wn * 64 + ni * 16 + lr;
      const int c = (c0 + crel);
      const int d = c & 63;
      const float bias = (mat == 0 ? bq : mat == 1 ? bk : bv)[c];
      f32x4 v = acc[mi][ni];
      if (mat < 2) {
        const int jj = d & 15, tt = d >> 4;
        const float fr = __expf(-(float)(jj & 14) * 0.5756462732485115f);
        const float sign = (d & 1) ? 1.f : -1.f;
        for (int j = 0; j < 4; ++j) {
          const int rrel = rrel_base + j;
          const float x = v[j] + bias;
          const float part = __shfl_xor(x, 1, 64);
          const int lqs = mloc + rrel;
          const float fq = temporal[((size_t)bb * LSEQ + lqs) * 4 + tt] * fr;
          float sn, cs;
          __sincosf(fq, &sn, &cs);
          otile[rrel * 136 + crel] = f2bf((x * cs + sign * part * sn) * qscale);
        }
      } else {
        for (int j = 0; j < 4; ++j) {
          const int rrel = rrel_base + j;
          otile[crel * 136 + rrel] = f2bf(v[j] + bias);
        }
      }
    }
  }
  __syncthreads();

  // ---- phase 2: coalesced 16B stores ----
  for (int i = 0; i < 2; ++i) {
    const int h = (c0 >> 6) + i;
    const size_t bh = (size_t)(bb * NH + h);
    if (mat == 0) {
      const size_t base = (bh * LSEQ + mloc) * 64;
#pragma unroll
      for (int kk2 = 0; kk2 < 4; ++kk2) {
        const int e = kk2 * 2048 + tid * 8;
        const int r = e >> 6, d = e & 63;
        *reinterpret_cast<u16x8*>(qbuf + base + e) =
            *reinterpret_cast<const u16x8*>(otile + r * 136 + i * 64 + d);
      }
    } else if (mat == 1) {
      const size_t base = bh * 131072 + (size_t)(mloc >> 5) * 2048;
#pragma unroll
      for (int kk2 = 0; kk2 < 4; ++kk2) {
        const int e = kk2 * 2048 + tid * 8;
        const int r = kk2 * 32 + ((tid >> 1) & 31);
        const int d = ((tid >> 6) & 3) * 16 + (tid & 1) * 8;
        *reinterpret_cast<u16x8*>(kbuf + base + e) =
            *reinterpret_cast<const u16x8*>(otile + r * 136 + i * 64 + d);
      }
    } else {
      const size_t base = bh * 131072 + (size_t)(mloc >> 4) * 1024;
#pragma unroll
      for (int kk2 = 0; kk2 < 4; ++kk2) {
        const int e = kk2 * 2048 + tid * 8;
        const int d = ((tid >> 6) & 1) * 32 + ((tid >> 1) & 31);
        const int rb = (kk2 * 2 + (tid >> 7)) * 16;
        const int dl = (tid & 1) * 4;
        const unsigned short* srow = otile + (i * 64 + d) * 136 + rb + dl;
        ushort4 lo = *reinterpret_cast<const ushort4*>(srow);
        ushort4 hi4 = *reinterpret_cast<const ushort4*>(srow + 8);
        u16x8 w;
        w[0] = lo.x; w[1] = lo.y; w[2] = lo.z; w[3] = lo.w;
        w[4] = hi4.x; w[5] = hi4.y; w[6] = hi4.z; w[7] = hi4.w;
        *reinterpret_cast<u16x8*>(vtbuf + base + e) = w;
      }
    }
  }
}

// ---------------- flash attention: QBLK=64/wave, kv-split x2, bh->XCD affine (r11) ----------------
__global__ __launch_bounds__(256) void k_attn(
    const unsigned short* __restrict__ qbuf, const unsigned short* __restrict__ kbuf,
    const unsigned short* __restrict__ vtbuf, const unsigned short* __restrict__ maskCb,
    const int* __restrict__ zflags, float* __restrict__ out) {
  __shared__ float obuf[2][64][68];      // [q-half][q-local][d]
  __shared__ float mlbuf[4][2][32][2];   // [wave][subtile][lane-q][m,l]
  const int tid = threadIdx.x, lane = tid & 63, wid = tid >> 6;
  const int lq = lane & 31, hi = lane >> 5;
  const int qh = wid & 1, kvh = wid >> 1;

  // bh->XCD affinity: xcd = bid&7; 4 bh per xcd; 16 q-blocks per bh
  const int bid = blockIdx.x;
  const int xcd = bid & 7, loc = bid >> 3;       // loc in [0,64)
  const int bh = xcd * 4 + (loc >> 4);
  const int qblk = loc & 15;

  const int q0 = qblk * 128 + qh * 64;
  const int qgA = q0 + lq, qgB = q0 + 32 + lq;
  const size_t bhL = (size_t)bh * LSEQ;
  const unsigned short* kb = kbuf + (size_t)bh * 131072;
  const unsigned short* vb = vtbuf + (size_t)bh * 131072;
  const unsigned short* mbA = maskCb + ((size_t)hi * 2048 + qgA) * 16;
  const unsigned short* mbB = maskCb + ((size_t)hi * 2048 + qgB) * 16;

  bf16x8 qfA[4], qfB[4];
#pragma unroll
  for (int c = 0; c < 4; ++c) {
    qfA[c] = *reinterpret_cast<const bf16x8*>(qbuf + (bhL + qgA) * 64 + c * 16 + hi * 8);
    qfB[c] = *reinterpret_cast<const bf16x8*>(qbuf + (bhL + qgB) * 64 + c * 16 + hi * 8);
  }

  f32x16 oA0 = {}, oA1 = {}, oB0 = {}, oB1 = {};
  float m2 = 2.0f, lA = 0.f, lB = 0.f;

  const int kv_beg = kvh * 1024, kv_end = kv_beg + 1024;
  for (int kv0 = kv_beg; kv0 < kv_end; kv0 += 64) {
    // mask C-init (one zflag covers the whole 64-q range of this wave)
    f32x16 sA0, sA1, sB0, sB1;
    const int zf = zflags[(kv0 >> 6) * 32 + (q0 >> 6)];
    if (zf) {
      sA0 = (f32x16){}; sA1 = (f32x16){};
      sB0 = (f32x16){}; sB1 = (f32x16){};
    } else {
      const size_t mo = (size_t)(kv0 >> 6) * (4 * 2048 * 16);
      const unsigned short* mtA = mbA + mo;
      const unsigned short* mtB = mbB + mo;
      sA0 = unpack16(*reinterpret_cast<const u16x8*>(mtA),
                     *reinterpret_cast<const u16x8*>(mtA + 8));
      sA1 = unpack16(*reinterpret_cast<const u16x8*>(mtA + 2 * 2048 * 16),
                     *reinterpret_cast<const u16x8*>(mtA + 2 * 2048 * 16 + 8));
      sB0 = unpack16(*reinterpret_cast<const u16x8*>(mtB),
                     *reinterpret_cast<const u16x8*>(mtB + 8));
      sB1 = unpack16(*reinterpret_cast<const u16x8*>(mtB + 2 * 2048 * 16),
                     *reinterpret_cast<const u16x8*>(mtB + 2 * 2048 * 16 + 8));
    }

    // S^T = K . Q^T + maskC : each K fragment feeds 2 MFMAs (subtiles A,B)
    const unsigned short* kch = kb + (size_t)(kv0 >> 5) * 2048;
#pragma unroll
    for (int c = 0; c < 4; ++c) {
      bf16x8 k0 = *reinterpret_cast<const bf16x8*>(kch + c * 512 + lq * 16 + hi * 8);
      bf16x8 k1 = *reinterpret_cast<const bf16x8*>(kch + 2048 + c * 512 + lq * 16 + hi * 8);
      sA0 = __builtin_amdgcn_mfma_f32_32x32x16_bf16(k0, qfA[c], sA0, 0, 0, 0);
      sB0 = __builtin_amdgcn_mfma_f32_32x32x16_bf16(k0, qfB[c], sB0, 0, 0, 0);
      sA1 = __builtin_amdgcn_mfma_f32_32x32x16_bf16(k1, qfA[c], sA1, 0, 0, 0);
      sB1 = __builtin_amdgcn_mfma_f32_32x32x16_bf16(k1, qfB[c], sB1, 0, 0, 0);
    }

    // V-load hoist: independent of softmax; issue now, consume ~500 cycles later
    const unsigned short* vch = vb + (size_t)(kv0 >> 4) * 1024;
    bf16x8 vf[8];
#pragma unroll
    for (int ks = 0; ks < 4; ++ks) {
      vf[2 * ks]     = *reinterpret_cast<const bf16x8*>(vch + ks * 1024 + lq * 16 + hi * 8);
      vf[2 * ks + 1] = *reinterpret_cast<const bf16x8*>(vch + ks * 1024 + 512 + lq * 16 + hi * 8);
    }

    // p = 2^(s - m2); row-sums
    float a0 = 0.f, a1 = 0.f, b0 = 0.f, b1 = 0.f;
#pragma unroll
    for (int r = 0; r < 8; ++r) {
      sA0[r] = exp2fast(sA0[r] - m2);     a0 += sA0[r];
      sA0[r + 8] = exp2fast(sA0[r + 8] - m2); a1 += sA0[r + 8];
      sB0[r] = exp2fast(sB0[r] - m2);     b0 += sB0[r];
      sB0[r + 8] = exp2fast(sB0[r + 8] - m2); b1 += sB0[r + 8];
    }
#pragma unroll
    for (int r = 0; r < 8; ++r) {
      sA1[r] = exp2fast(sA1[r] - m2);     a0 += sA1[r];
      sA1[r + 8] = exp2fast(sA1[r + 8] - m2); a1 += sA1[r + 8];
      sB1[r] = exp2fast(sB1[r] - m2);     b0 += sB1[r];
      sB1[r + 8] = exp2fast(sB1[r + 8] - m2); b1 += sB1[r + 8];
    }
    float rsA = a0 + a1, rsB = b0 + b1;

    // overflow guard: rs <= 2048 bounds P <= 2048 (rare bump path)
    if (__any(fmaxf(rsA, rsB) > 2048.f)) {
      const float cc = 0.000244140625f;   // 2^-12
#pragma unroll
      for (int r = 0; r < 16; ++r) {
        sA0[r] *= cc; sA1[r] *= cc; sB0[r] *= cc; sB1[r] *= cc;
        oA0[r] *= cc; oA1[r] *= cc; oB0[r] *= cc; oB1[r] *= cc;
      }
      rsA *= cc; rsB *= cc; lA *= cc; lB *= cc;
      m2 += 12.f;
    }

    rsA += __shfl_xor(rsA, 32, 64);
    rsB += __shfl_xor(rsB, 32, 64);
    lA += rsA; lB += rsB;

    // P -> bf16 fragments (natural order; V stored k-permuted)
    bf16x8 pfA0 = pack8(sA0, 0), pfA1 = pack8(sA0, 8);
    bf16x8 pfA2 = pack8(sA1, 0), pfA3 = pack8(sA1, 8);
    bf16x8 pfB0 = pack8(sB0, 0), pfB1 = pack8(sB0, 8);
    bf16x8 pfB2 = pack8(sB1, 0), pfB3 = pack8(sB1, 8);

    // O^T += V . P : each V fragment feeds 2 MFMAs (subtiles A,B)
#pragma unroll
    for (int ks = 0; ks < 4; ++ks) {
      bf16x8 pfA = (ks == 0) ? pfA0 : (ks == 1) ? pfA1 : (ks == 2) ? pfA2 : pfA3;
      bf16x8 pfB = (ks == 0) ? pfB0 : (ks == 1) ? pfB1 : (ks == 2) ? pfB2 : pfB3;
      oA0 = __builtin_amdgcn_mfma_f32_32x32x16_bf16(vf[2 * ks], pfA, oA0, 0, 0, 0);
      oB0 = __builtin_amdgcn_mfma_f32_32x32x16_bf16(vf[2 * ks], pfB, oB0, 0, 0, 0);
      oA1 = __builtin_amdgcn_mfma_f32_32x32x16_bf16(vf[2 * ks + 1], pfA, oA1, 0, 0, 0);
      oB1 = __builtin_amdgcn_mfma_f32_32x32x16_bf16(vf[2 * ks + 1], pfB, oB1, 0, 0, 0);
    }
  }

  // ---- merge: exchange (m,l); kvh=0 stages scaled O in LDS; kvh=1 adds + stores ----
  if (lane < 32) {
    mlbuf[wid][0][lq][0] = m2; mlbuf[wid][0][lq][1] = lA;
    mlbuf[wid][1][lq][0] = m2; mlbuf[wid][1][lq][1] = lB;
  }
  __syncthreads();
  const int pw = wid ^ 2;                     // partner wave (other kv-half)
  const float mAp = mlbuf[pw][0][lq][0], lAp = mlbuf[pw][0][lq][1];
  const float mBp = mlbuf[pw][1][lq][0], lBp = mlbuf[pw][1][lq][1];
  const float msA = fmaxf(m2, mAp);
  const float fA = exp2fast(m2 - msA), fAp = exp2fast(mAp - msA);
  const float scaleA = fA / (lA * fA + lAp * fAp);
  const float msB = fmaxf(m2, mBp);
  const float fB = exp2fast(m2 - msB), fBp = exp2fast(mBp - msB);
  const float scaleB = fB / (lB * fB + lBp * fBp);

  if (kvh == 0) {
#pragma unroll
    for (int g = 0; g < 4; ++g) {
      const int d0 = 8 * g + 4 * hi;
      float4 wA0 = make_float4(oA0[4 * g] * scaleA, oA0[4 * g + 1] * scaleA,
                               oA0[4 * g + 2] * scaleA, oA0[4 * g + 3] * scaleA);
      float4 wA1 = make_float4(oA1[4 * g] * scaleA, oA1[4 * g + 1] * scaleA,
                               oA1[4 * g + 2] * scaleA, oA1[4 * g + 3] * scaleA);
      float4 wB0 = make_float4(oB0[4 * g] * scaleB, oB0[4 * g + 1] * scaleB,
                               oB0[4 * g + 2] * scaleB, oB0[4 * g + 3] * scaleB);
      float4 wB1 = make_float4(oB1[4 * g] * scaleB, oB1[4 * g + 1] * scaleB,
                               oB1[4 * g + 2] * scaleB, oB1[4 * g + 3] * scaleB);
      *reinterpret_cast<float4*>(&obuf[qh][lq][d0])           = wA0;
      *reinterpret_cast<float4*>(&obuf[qh][lq][d0 + 32])      = wA1;
      *reinterpret_cast<float4*>(&obuf[qh][32 + lq][d0])      = wB0;
      *reinterpret_cast<float4*>(&obuf[qh][32 + lq][d0 + 32]) = wB1;
    }
  }
  __syncthreads();
  if (kvh == 1) {
    const int b = bh >> 4, h = bh & 15;
    float* orowA = out + (size_t)(b * LSEQ + qgA) * DM + h * 64;
    float* orowB = out + (size_t)(b * LSEQ + qgB) * DM + h * 64;
#pragma unroll
    for (int g = 0; g < 4; ++g) {
      const int d0 = 8 * g + 4 * hi;
      float4 pA0 = *reinterpret_cast<const float4*>(&obuf[qh][lq][d0]);
      float4 pA1 = *reinterpret_cast<const float4*>(&obuf[qh][lq][d0 + 32]);
      float4 pB0 = *reinterpret_cast<const float4*>(&obuf[qh][32 + lq][d0]);
      float4 pB1 = *reinterpret_cast<const float4*>(&obuf[qh][32 + lq][d0 + 32]);
      float4 wA0 = make_float4(pA0.x + oA0[4 * g] * scaleA, pA0.y + oA0[4 * g + 1] * scaleA,
                               pA0.z + oA0[4 * g + 2] * scaleA, pA0.w + oA0[4 * g + 3] * scaleA);
      float4 wA1 = make_float4(pA1.x + oA1[4 * g] * scaleA, pA1.y + oA1[4 * g + 1] * scaleA,
                               pA1.z + oA1[4 * g + 2] * scaleA, pA1.w + oA1[4 * g + 3] * scaleA);
      float4 wB0 = make_float4(pB0.x + oB0[4 * g] * scaleB, pB0.y + oB0[4 * g + 1] * scaleB,
                               pB0.z + oB0[4 * g + 2] * scaleB, pB0.w + oB0[4 * g + 3] * scaleB);
      float4 wB1 = make_float4(pB1.x + oB1[4 * g] * scaleB, pB1.y + oB1[4 * g + 1] * scaleB,
                               pB1.z + oB1[4 * g + 2] * scaleB, pB1.w + oB1[4 * g + 3] * scaleB);
      *reinterpret_cast<float4*>(orowA + d0)      = wA0;
      *reinterpret_cast<float4*>(orowA + d0 + 32) = wA1;
      *reinterpret_cast<float4*>(orowB + d0)      = wB0;
      *reinterpret_cast<float4*>(orowB + d0 + 32) = wB1;
    }
  }
}

extern "C" void kernel_launch(void* const* d_in, const int* in_sizes, int n_in,
                              void* d_out, int out_size, void* d_ws, size_t ws_size,
                              hipStream_t stream) {
  const float* data     = (const float*)d_in[0];
  const float* temporal = (const float*)d_in[1];
  const float* mask     = (const float*)d_in[2];
  const float* Wq       = (const float*)d_in[3];
  const float* bq       = (const float*)d_in[4];
  const float* Wk       = (const float*)d_in[5];
  const float* bk       = (const float*)d_in[6];
  const float* Wv       = (const float*)d_in[7];
  const float* bv       = (const float*)d_in[8];
  float* out = (float*)d_out;

  char* ws = (char*)d_ws;
  unsigned short* data_bf = (unsigned short*)(ws);                        // 8 MB (reused by maskCb)
  unsigned short* wt      = (unsigned short*)(ws + (size_t)8  * 1048576); // 6 MB (dead after gemm)
  unsigned short* qbuf    = (unsigned short*)(ws + (size_t)14 * 1048576); // 8 MB
  unsigned short* kbuf    = (unsigned short*)(ws + (size_t)22 * 1048576); // 8 MB
  unsigned short* vtbuf   = (unsigned short*)(ws + (size_t)30 * 1048576); // 8 MB
  unsigned short* maskCb  = (unsigned short*)(ws + (size_t)38 * 1048576); // 8 MB (own region: written concurrently with gemm)
  int* zflags             = (int*)(ws + (size_t)46 * 1048576);            // 4 KB

  hipLaunchKernelGGL(k_prep, dim3(4096 + 768), dim3(256), 0, stream,
                     data, data_bf, (2 * LSEQ * DM) / 4, Wq, Wk, Wv, wt);
  hipLaunchKernelGGL(k_qkv_gemm, dim3(768 + 1024), dim3(256), 0, stream,
                     data_bf, wt, bq, bk, bv, temporal, qbuf, kbuf, vtbuf,
                     mask, maskCb, zflags);
  hipLaunchKernelGGL(k_attn, dim3(512), dim3(256), 0, stream,
                     qbuf, kbuf, vtbuf, maskCb, zflags, out);
}